// Round 3
// baseline (230.083 us; speedup 1.0000x reference)
//
#include <hip/hip_runtime.h>

#define L 256
#define BATCH 512
#define CIN 32
#define HIDN 128
#define OUTN 512

typedef _Float16 f16x8 __attribute__((ext_vector_type(8)));
typedef float f32x4 __attribute__((ext_vector_type(4)));

#define MFMA16(a, b, c) __builtin_amdgcn_mfma_f32_16x16x32_f16(a, b, c, 0, 0, 0)

static __device__ __forceinline__ unsigned short f16b(_Float16 h) {
    unsigned short u; __builtin_memcpy(&u, &h, 2); return u;
}

// ws layout (bytes):
//   Wh   @ 0        (32768)  fp16 hi of W_hh [j][k]
//   Wl   @ 32768    (32768)  fp16 lo residual
//   Wch  @ 65536    (8192)   fp16 hi of Wc = W_ih@W_in [j][c]
//   Wcl  @ 73728    (8192)
//   bpre @ 81920    (512)    fp32 b_ih + b_hh + W_ih@b_in
//   hs   @ 98304    (33554432) fp16 hs[t*65536 + b*128 + j]
//   xT   @ 33652736 (8421376)  fp16 xT[t][b][c], 257 t-slots

// Block 0: weights (W_ih/b_in staged in LDS: the old serial dependent-global
// chain was ~6 us on one CU). Blocks 1..64: transpose x -> xT, split 2-way in
// t so it uses 64 CUs instead of 32.
__global__ __launch_bounds__(256) void prep_kernel(
    const float* __restrict__ x,
    const float* __restrict__ W_in, const float* __restrict__ b_in,
    const float* __restrict__ W_ih, const float* __restrict__ b_ih,
    const float* __restrict__ b_hh, const float* __restrict__ Whh,
    unsigned short* __restrict__ Wh, unsigned short* __restrict__ Wl,
    unsigned short* __restrict__ Wch, unsigned short* __restrict__ Wcl,
    float* __restrict__ bpre, unsigned short* __restrict__ xT)
{
    const int tid = threadIdx.x;

    if (blockIdx.x != 0) {
        // ---- transpose: 16 batch rows, 4 t-chunks of 32 per block ----
        const int idx0 = blockIdx.x - 1;
        const int bb = idx0 & 31;          // batch group
        const int half = idx0 >> 5;        // t half
        __shared__ float tile[32][16][33];   // [t_local][n][c] f32, swizzled
        const int wv = tid >> 6, l = tid & 63;
        const int wn = l >> 2, wc0 = (l & 3) * 8;
        for (int tc = half * 4; tc < half * 4 + 4; ++tc) {
#pragma unroll
            for (int r = 0; r < 16; ++r) {
                int i = tid + r * 256;            // 16n x 32c x 8tq float4s
                int nn = i >> 8, cc = (i >> 3) & 31, tq = i & 7;
                float4 v = *(const float4*)(
                    x + ((size_t)(bb * 16 + nn) * CIN + cc) * L + tc * 32 + tq * 4);
                int cs = cc ^ ((tq & 3) << 3);    // spread banks over tq
                tile[tq * 4 + 0][nn][cs] = v.x;
                tile[tq * 4 + 1][nn][cs] = v.y;
                tile[tq * 4 + 2][nn][cs] = v.z;
                tile[tq * 4 + 3][nn][cs] = v.w;
            }
            __syncthreads();
#pragma unroll
            for (int it = 0; it < 8; ++it) {
                int tl = wv + it * 4;
                int swz = ((tl >> 2) & 3) << 3;
                const float* src = &tile[tl][wn][wc0 ^ swz];
                unsigned short o[8];
#pragma unroll
                for (int k = 0; k < 8; ++k) o[k] = f16b((_Float16)src[k]);
                *(uint4*)(xT + ((size_t)(tc * 32 + tl) * BATCH + bb * 16 + wn) * CIN + wc0)
                    = *(uint4*)o;
            }
            __syncthreads();
        }
        return;
    }

    // ---- block 0: weights ----
    __shared__ float win[64 * CIN];      // 8 KB
    __shared__ float wih[128 * 64];      // 32 KB
    __shared__ float binS[64];
    for (int i = tid; i < 64 * CIN; i += 256) win[i] = W_in[i];
    for (int i = tid; i < 128 * 64; i += 256) wih[i] = W_ih[i];
    if (tid < 64) binS[tid] = b_in[tid];
    __syncthreads();
    if (tid < 128) {
        const int j = tid;
        float acc[CIN];
#pragma unroll
        for (int c = 0; c < CIN; ++c) acc[c] = 0.f;
        float bs = b_ih[j] + b_hh[j];
        for (int m = 0; m < 64; ++m) {
            float w = wih[j * 64 + m];
            bs += w * binS[m];
#pragma unroll
            for (int c = 0; c < CIN; ++c) acc[c] += w * win[m * CIN + c];
        }
        bpre[j] = bs;
#pragma unroll
        for (int c = 0; c < CIN; ++c) {
            _Float16 h = (_Float16)acc[c];
            _Float16 lo = (_Float16)(acc[c] - (float)h);
            Wch[j * CIN + c] = f16b(h);
            Wcl[j * CIN + c] = f16b(lo);
        }
    } else {
        const int j = tid - 128;
        for (int k = 0; k < HIDN; k += 4) {
            float4 v = *(const float4*)(Whh + j * HIDN + k);
            float vv[4] = {v.x, v.y, v.z, v.w};
#pragma unroll
            for (int u = 0; u < 4; ++u) {
                _Float16 h = (_Float16)vv[u];
                _Float16 lo = (_Float16)(vv[u] - (float)h);
                Wh[j * HIDN + k + u] = f16b(h);
                Wl[j * HIDN + k + u] = f16b(lo);
            }
        }
    }
}

// MFMA RNN, fp16 2-term split. 32 blocks (16 batch rows) x 512 thr (8 waves).
// R12: x path fully off the LDS unit. x comes from pre-transposed xT via
// register half-windows xa[8]/xb[8] (statically indexed -> stay in VGPRs),
// refilled 8 steps (~4800 cyc) ahead of first use so even HBM-cold loads
// retire in time — this is the depth R10 lacked (1-step lead = per-step
// stalls). Compiler's exact per-register vmcnt counting keeps hs stores and
// refills in flight across barriers; nothing ever drains vmcnt. Per step per
// CU the LDS unit now serves only 8 waves x (4 b128 hbuf reads + 1 b64
// h-write); the staging-write conflicts and the xc read are gone. Barrier
// guard back to lgkmcnt(0).
__global__ __launch_bounds__(512, 1) void rnn_kernel(
    const float* __restrict__ h0,
    const unsigned short* __restrict__ Wh, const unsigned short* __restrict__ Wl,
    const unsigned short* __restrict__ Wch, const unsigned short* __restrict__ Wcl,
    const float* __restrict__ bpre, const unsigned short* __restrict__ xT,
    unsigned short* __restrict__ hs)
{
    const int tid = threadIdx.x;
    const int bb = blockIdx.x;
    const int lane = tid & 63;
    const int w = tid >> 6;       // wave 0..7
    const int n = lane & 15;      // batch col / B col
    const int q = lane >> 4;      // quad

    __shared__ unsigned short hbuf[2][16][HIDN];     // 8 KB, granule swizzle ^(n&7)

    // x stream: lane (n,q) reads xT[t][bb*16+n][q*8..+8]; issue first two
    // half-windows immediately for maximum lead.
    const unsigned short* xq = xT + ((size_t)(bb * 16 + n) * CIN + q * 8);
    f16x8 xa[8], xb[8];
#define ISSUE8(ARR, TB)                                                        \
    do {                                                                       \
        _Pragma("unroll")                                                      \
        for (int ii = 0; ii < 8; ++ii)                                         \
            ARR[ii] = *(const f16x8*)(xq + (size_t)((TB) + ii) * (BATCH * CIN)); \
    } while (0)
    ISSUE8(xa, 0);
    ISSUE8(xb, 8);

    // A-frags: rows = j = w*16 + n
    f16x8 Ah[4], Al[4], Axh, Axl;
    const int jr = w * 16 + n;
#pragma unroll
    for (int kc = 0; kc < 4; ++kc) {
        Ah[kc] = *(const f16x8*)(Wh + jr * HIDN + kc * 32 + q * 8);
        Al[kc] = *(const f16x8*)(Wl + jr * HIDN + kc * 32 + q * 8);
    }
    Axh = *(const f16x8*)(Wch + jr * CIN + q * 8);
    Axl = *(const f16x8*)(Wcl + jr * CIN + q * 8);
    float4 bv = *(const float4*)(bpre + w * 16 + q * 4);
    f32x4 bp = (f32x4){bv.x, bv.y, bv.z, bv.w};
    const f32x4 zero4 = (f32x4){0.f, 0.f, 0.f, 0.f};

    // ---- h0 -> fp16 plane, dbuf 0 (first 256 threads) ----
    if (tid < 256) {
        const int ni = tid >> 4, gi = tid & 15;
        const float4* src = (const float4*)(h0 + ((size_t)bb * 16 + ni) * HIDN + gi * 8);
        float4 a = src[0], b4 = src[1];
        float vv[8] = {a.x, a.y, a.z, a.w, b4.x, b4.y, b4.z, b4.w};
        unsigned short o[8];
#pragma unroll
        for (int i = 0; i < 8; ++i) o[i] = f16b((_Float16)vv[i]);
        *(uint4*)&hbuf[0][ni][(gi ^ (ni & 7)) * 8] = *(uint4*)o;
    }
    __syncthreads();

    unsigned short* hsp = hs + ((size_t)bb * 16 + n) * HIDN + w * 16 + q * 4;
    const int G = (w * 2 + (q >> 1)) ^ (n & 7);
    const int sw = n & 7;

#define STEP(K, XCUR)                                                          \
    {                                                                          \
        const int IN = (K) & 1, OUT = IN ^ 1;                                  \
        f16x8 Bh0 = *(const f16x8*)&hbuf[IN][n][((0 + q) ^ sw) * 8];           \
        f16x8 Bh1 = *(const f16x8*)&hbuf[IN][n][((4 + q) ^ sw) * 8];           \
        f16x8 Bh2 = *(const f16x8*)&hbuf[IN][n][((8 + q) ^ sw) * 8];           \
        f16x8 Bh3 = *(const f16x8*)&hbuf[IN][n][((12 + q) ^ sw) * 8];          \
        f32x4 c0 = MFMA16(Axh, XCUR, bp);      /* operands all in regs */      \
        f32x4 c2 = MFMA16(Axl, XCUR, zero4);                                   \
        c0 = MFMA16(Ah[0], Bh0, c0);                                           \
        c2 = MFMA16(Al[0], Bh0, c2);                                           \
        f32x4 c1 = MFMA16(Ah[1], Bh1, zero4);                                  \
        f32x4 c3 = MFMA16(Al[1], Bh1, zero4);                                  \
        c0 = MFMA16(Ah[2], Bh2, c0);                                           \
        c2 = MFMA16(Al[2], Bh2, c2);                                           \
        c1 = MFMA16(Ah[3], Bh3, c1);                                           \
        c3 = MFMA16(Al[3], Bh3, c3);                                           \
        f32x4 acc = (c0 + c1) + (c2 + c3);                                     \
        unsigned short o[4];                                                   \
        for (int r = 0; r < 4; ++r) {                                          \
            float e = __expf(2.f * acc[r]);                                    \
            float hv = 1.f - 2.f * __builtin_amdgcn_rcpf(e + 1.f);             \
            o[r] = f16b((_Float16)hv);                                         \
        }                                                                      \
        uint2 pk; __builtin_memcpy(&pk, o, 8);                                 \
        *(uint2*)&hbuf[OUT][n][G * 8 + (q & 1) * 4] = pk;                      \
        *(uint2*)(hsp + (K) * (BATCH * HIDN)) = pk;                            \
        asm volatile("" ::: "memory");                                         \
        __builtin_amdgcn_s_waitcnt(0xC07F);  /* lgkmcnt(0); vmem in flight */  \
        __builtin_amdgcn_s_barrier();                                          \
        asm volatile("" ::: "memory");                                         \
    }

    for (int tc = 0; tc < 16; ++tc) {
        STEP(0, xa[0]); STEP(1, xa[1]); STEP(2, xa[2]); STEP(3, xa[3]);
        STEP(4, xa[4]); STEP(5, xa[5]); STEP(6, xa[6]); STEP(7, xa[7]);
        if (tc < 15) ISSUE8(xa, tc * 16 + 16);   // 8-step lead to next window
        STEP(8, xb[0]); STEP(9, xb[1]); STEP(10, xb[2]); STEP(11, xb[3]);
        STEP(12, xb[4]); STEP(13, xb[5]); STEP(14, xb[6]); STEP(15, xb[7]);
        if (tc < 15) ISSUE8(xb, tc * 16 + 24);   // 8-step lead
        hsp += 16 * (BATCH * HIDN);
    }
#undef STEP
#undef ISSUE8
}

// Fused upsample(16->32, align_corners) + hardswish + mean + out-GEMM.
__global__ __launch_bounds__(256) void pool_out_kernel(
    const unsigned short* __restrict__ hs, const float* __restrict__ W_out,
    const float* __restrict__ b_out, float* __restrict__ out)
{
    const int b = blockIdx.x, tid = threadIdx.x;
    __shared__ unsigned short m[L][HIDN];   // 64 KB fp16
    __shared__ float ps[2][HIDN];
    __shared__ float pooled_s[HIDN];

#pragma unroll
    for (int it = 0; it < 16; ++it) {
        int i = tid + it * 256;             // uint4 granule = 8 fp16
        int t = i >> 4, g = i & 15;
        *(uint4*)&m[t][g * 8] =
            *(const uint4*)(hs + (size_t)t * (BATCH * HIDN) + b * HIDN + g * 8);
    }
    __syncthreads();

    const int jo = tid & 127, sub = tid >> 7;
    float acc = 0.f;
    for (int oy = sub * 16; oy < sub * 16 + 16; ++oy) {
        float ysf = oy * (15.f / 31.f);
        int y0 = (int)ysf; float wy = ysf - (float)y0; int y1 = min(y0 + 1, 15);
        float rb[16];
#pragma unroll
        for (int sx = 0; sx < 16; ++sx) {
            float v0 = (float)*(const _Float16*)&m[y0 * 16 + sx][jo];
            float v1 = (float)*(const _Float16*)&m[y1 * 16 + sx][jo];
            rb[sx] = v0 + wy * (v1 - v0);
        }
#pragma unroll
        for (int ox = 0; ox < 32; ++ox) {
            float xsf = ox * (15.f / 31.f);
            int x0 = (int)xsf; float wx = xsf - (float)x0; int x1 = min(x0 + 1, 15);
            float v = rb[x0] + wx * (rb[x1] - rb[x0]);
            float t6 = fminf(fmaxf(v + 3.f, 0.f), 6.f);
            acc += v * t6;
        }
    }
    ps[sub][jo] = acc;
    __syncthreads();
    if (tid < 128) pooled_s[tid] = (ps[0][tid] + ps[1][tid]) * (1.f / 6144.f);
    __syncthreads();

    for (int o = tid; o < OUTN; o += 256) {
        float a = b_out[o];
#pragma unroll 8
        for (int k = 0; k < HIDN; k += 4) {
            float4 wv = *(const float4*)(W_out + o * HIDN + k);
            float4 pv = *(const float4*)&pooled_s[k];   // broadcast b128
            a += wv.x * pv.x + wv.y * pv.y + wv.z * pv.z + wv.w * pv.w;
        }
        out[b * OUTN + o] = a;
    }
}

extern "C" void kernel_launch(void* const* d_in, const int* in_sizes, int n_in,
                              void* d_out, int out_size, void* d_ws, size_t ws_size,
                              hipStream_t stream)
{
    const float* x     = (const float*)d_in[0];
    const float* h0    = (const float*)d_in[1];
    const float* W_in  = (const float*)d_in[2];
    const float* b_in  = (const float*)d_in[3];
    const float* W_ih  = (const float*)d_in[4];
    const float* b_ih  = (const float*)d_in[5];
    const float* W_hh  = (const float*)d_in[6];
    const float* b_hh  = (const float*)d_in[7];
    const float* W_out = (const float*)d_in[8];
    const float* b_out = (const float*)d_in[9];
    float* out = (float*)d_out;

    char* wsb = (char*)d_ws;
    unsigned short* Wh  = (unsigned short*)(wsb);
    unsigned short* Wl  = (unsigned short*)(wsb + 32768);
    unsigned short* Wch = (unsigned short*)(wsb + 65536);
    unsigned short* Wcl = (unsigned short*)(wsb + 73728);
    float* bpre         = (float*)(wsb + 81920);
    unsigned short* hsb = (unsigned short*)(wsb + 98304);
    unsigned short* xT  = (unsigned short*)(wsb + 33652736);  // 257*512*32 fp16

    prep_kernel<<<65, 256, 0, stream>>>(x, W_in, b_in, W_ih, b_ih, b_hh, W_hh,
                                        Wh, Wl, Wch, Wcl, bpre, xT);
    rnn_kernel<<<32, 512, 0, stream>>>(h0, Wh, Wl, Wch, Wcl, bpre, xT, hsb);
    pool_out_kernel<<<512, 256, 0, stream>>>(hsb, W_out, b_out, out);
}